// Round 1
// baseline (1395.072 us; speedup 1.0000x reference)
//
#include <hip/hip_runtime.h>
#include <stdint.h>

typedef short bf16x8 __attribute__((ext_vector_type(8)));
typedef float f32x4  __attribute__((ext_vector_type(4)));

constexpr int BT = 4096;   // tokens
constexpr int DD = 1024;   // model dim
constexpr int OO = 1024;   // output dim
constexpr int EE = 8;      // experts
constexpr int HH = 4096;   // hidden dim

__device__ __forceinline__ unsigned short f2bf(float f) {
  unsigned u = __float_as_uint(f);
  u += 0x7fffu + ((u >> 16) & 1u);   // round-to-nearest-even
  return (unsigned short)(u >> 16);
}

// ---------------- x -> bf16 ----------------
__global__ __launch_bounds__(256) void cvt_x_k(const float* __restrict__ x,
                                               unsigned short* __restrict__ xb) {
  int i = blockIdx.x * 256 + threadIdx.x;          // one float4 per thread
  float4 v = ((const float4*)x)[i];
  unsigned a = (unsigned)f2bf(v.x) | ((unsigned)f2bf(v.y) << 16);
  unsigned b = (unsigned)f2bf(v.z) | ((unsigned)f2bf(v.w) << 16);
  ((uint2*)xb)[i] = make_uint2(a, b);
}

// ------- transpose+convert: src fp32 [E][R][C] -> dst bf16 [E][C][R] -------
__global__ __launch_bounds__(256) void cvt_t_k(const float* __restrict__ src,
                                               unsigned short* __restrict__ dst,
                                               int R, int C) {
  __shared__ unsigned short tile[64][68];
  int e = blockIdx.z;
  const float* s = src + (size_t)e * R * C;
  unsigned short* d = dst + (size_t)e * R * C;
  int r0 = blockIdx.x << 6, c0 = blockIdx.y << 6;
  int t = threadIdx.x;
#pragma unroll
  for (int p = 0; p < 4; ++p) {                    // 1024 float4 chunks
    int ch = p * 256 + t;
    int rr = ch >> 4, cc = (ch & 15) << 2;
    float4 v = *(const float4*)&s[(size_t)(r0 + rr) * C + c0 + cc];
    unsigned lo = (unsigned)f2bf(v.x) | ((unsigned)f2bf(v.y) << 16);
    unsigned hi = (unsigned)f2bf(v.z) | ((unsigned)f2bf(v.w) << 16);
    *(uint2*)&tile[rr][cc] = make_uint2(lo, hi);
  }
  __syncthreads();
#pragma unroll
  for (int p = 0; p < 4; ++p) {
    int ch = p * 256 + t;
    int cc = ch >> 4, rr = (ch & 15) << 2;         // write 4 consecutive r
    unsigned short v0 = tile[rr + 0][cc];
    unsigned short v1 = tile[rr + 1][cc];
    unsigned short v2 = tile[rr + 2][cc];
    unsigned short v3 = tile[rr + 3][cc];
    unsigned lo = (unsigned)v0 | ((unsigned)v1 << 16);
    unsigned hi = (unsigned)v2 | ((unsigned)v3 << 16);
    *(uint2*)&d[(size_t)(c0 + cc) * R + r0 + rr] = make_uint2(lo, hi);
  }
}

// ---------------- router: logits, top-2, softmax, build lists ----------------
__global__ __launch_bounds__(256) void router_k(const float* __restrict__ x,
                                                const float* __restrict__ gw,
                                                const float* __restrict__ gb,
                                                int* __restrict__ cnt,
                                                int* __restrict__ list,
                                                float* __restrict__ rw) {
  int wave = threadIdx.x >> 6, lane = threadIdx.x & 63;
  int b = blockIdx.x * 4 + wave;
  float acc[8];
#pragma unroll
  for (int e = 0; e < 8; ++e) acc[e] = 0.f;
  for (int d = lane; d < DD; d += 64) {
    float xv = x[(size_t)b * DD + d];
    const float* g = &gw[d * 8];
    float4 g0 = *(const float4*)&g[0];
    float4 g1 = *(const float4*)&g[4];
    acc[0] += xv * g0.x; acc[1] += xv * g0.y; acc[2] += xv * g0.z; acc[3] += xv * g0.w;
    acc[4] += xv * g1.x; acc[5] += xv * g1.y; acc[6] += xv * g1.z; acc[7] += xv * g1.w;
  }
#pragma unroll
  for (int off = 32; off > 0; off >>= 1) {
#pragma unroll
    for (int e = 0; e < 8; ++e) acc[e] += __shfl_down(acc[e], off);
  }
  if (lane == 0) {
    float v[8];
#pragma unroll
    for (int e = 0; e < 8; ++e) v[e] = acc[e] + gb[e];
    int i0 = 0;
#pragma unroll
    for (int e = 1; e < 8; ++e) if (v[e] > v[i0]) i0 = e;
    int i1 = (i0 == 0) ? 1 : 0;
#pragma unroll
    for (int e = 0; e < 8; ++e) if (e != i0 && v[e] > v[i1]) i1 = e;
    float e1 = __expf(v[i1] - v[i0]);
    float inv = 1.0f / (1.0f + e1);
    float r0 = inv, r1 = e1 * inv;
    int p0 = atomicAdd(&cnt[i0], 1);
    list[i0 * BT + p0] = 2 * b;     rw[2 * b]     = r0;
    int p1 = atomicAdd(&cnt[i1], 1);
    list[i1 * BT + p1] = 2 * b + 1; rw[2 * b + 1] = r1;
  }
}

// ---------------- GEMM1: h[slot] = relu(x[tok] @ w1[e] + b1[e]) ----------------
__global__ __launch_bounds__(256) void gemm1_k(const unsigned short* __restrict__ xb,
                                               const unsigned short* __restrict__ w1t,
                                               const float* __restrict__ b1,
                                               const int* __restrict__ cnt,
                                               const int* __restrict__ list,
                                               unsigned short* __restrict__ h) {
  int e = blockIdx.z;
  int cnt_e = cnt[e];
  int m0 = blockIdx.x * 128;
  if (m0 >= cnt_e) return;
  int n0 = blockIdx.y * 128;

  __shared__ int slotbuf[128];
  __shared__ __align__(16) unsigned short Abuf[128 * 72];
  __shared__ __align__(16) unsigned short Bbuf[128 * 72];

  int t = threadIdx.x;
  if (t < 128) {
    int r = m0 + t;
    slotbuf[t] = list[e * BT + (r < cnt_e ? r : 0)];
  }
  __syncthreads();

  int wave = t >> 6, lane = t & 63;
  int wm = (wave & 1) * 64, wn = (wave >> 1) * 64;
  int lm = lane & 15, lq = lane >> 4;

  f32x4 acc[4][4];
#pragma unroll
  for (int mi = 0; mi < 4; ++mi)
#pragma unroll
    for (int ni = 0; ni < 4; ++ni) acc[mi][ni] = f32x4{0.f, 0.f, 0.f, 0.f};

  const unsigned short* Bsrc = w1t + (size_t)e * HH * DD + (size_t)n0 * DD;

  for (int k0 = 0; k0 < DD; k0 += 64) {
#pragma unroll
    for (int p = 0; p < 4; ++p) {
      int c = p * 256 + t;
      int row = c >> 3, kc = (c & 7) * 8;
      int tok = slotbuf[row] >> 1;
      uint4 v = *(const uint4*)&xb[(size_t)tok * DD + k0 + kc];
      *(uint4*)&Abuf[row * 72 + kc] = v;
    }
#pragma unroll
    for (int p = 0; p < 4; ++p) {
      int c = p * 256 + t;
      int row = c >> 3, kc = (c & 7) * 8;
      uint4 v = *(const uint4*)&Bsrc[(size_t)row * DD + k0 + kc];
      *(uint4*)&Bbuf[row * 72 + kc] = v;
    }
    __syncthreads();
#pragma unroll
    for (int ks = 0; ks < 64; ks += 32) {
      bf16x8 af[4], bf[4];
#pragma unroll
      for (int mi = 0; mi < 4; ++mi)
        af[mi] = *(const bf16x8*)&Abuf[(wm + mi * 16 + lm) * 72 + ks + lq * 8];
#pragma unroll
      for (int ni = 0; ni < 4; ++ni)
        bf[ni] = *(const bf16x8*)&Bbuf[(wn + ni * 16 + lm) * 72 + ks + lq * 8];
#pragma unroll
      for (int mi = 0; mi < 4; ++mi)
#pragma unroll
        for (int ni = 0; ni < 4; ++ni)
          acc[mi][ni] = __builtin_amdgcn_mfma_f32_16x16x32_bf16(af[mi], bf[ni], acc[mi][ni], 0, 0, 0);
    }
    __syncthreads();
  }

#pragma unroll
  for (int ni = 0; ni < 4; ++ni) {
    int ncol = n0 + wn + ni * 16 + lm;
    float bias = b1[e * HH + ncol];
#pragma unroll
    for (int mi = 0; mi < 4; ++mi) {
      int mbase = wm + mi * 16 + lq * 4;
#pragma unroll
      for (int r = 0; r < 4; ++r) {
        int mrow = mbase + r;
        if (m0 + mrow < cnt_e) {
          float v = acc[mi][ni][r] + bias;
          v = fmaxf(v, 0.0f);
          h[(size_t)slotbuf[mrow] * HH + ncol] = f2bf(v);
        }
      }
    }
  }
}

// -------- GEMM2: out[tok] += rw[slot] * (h[slot] @ w2[e] + b2[e]) --------
__global__ __launch_bounds__(256) void gemm2_k(const unsigned short* __restrict__ h,
                                               const unsigned short* __restrict__ w2t,
                                               const float* __restrict__ b2,
                                               const int* __restrict__ cnt,
                                               const int* __restrict__ list,
                                               const float* __restrict__ rw,
                                               float* __restrict__ out) {
  int e = blockIdx.z;
  int cnt_e = cnt[e];
  int m0 = blockIdx.x * 128;
  if (m0 >= cnt_e) return;
  int n0 = blockIdx.y * 128;

  __shared__ int slotbuf[128];
  __shared__ float rwbuf[128];
  __shared__ __align__(16) unsigned short Abuf[128 * 72];
  __shared__ __align__(16) unsigned short Bbuf[128 * 72];

  int t = threadIdx.x;
  if (t < 128) {
    int r = m0 + t;
    int s_ = list[e * BT + (r < cnt_e ? r : 0)];
    slotbuf[t] = s_;
    rwbuf[t] = rw[s_];
  }
  __syncthreads();

  int wave = t >> 6, lane = t & 63;
  int wm = (wave & 1) * 64, wn = (wave >> 1) * 64;
  int lm = lane & 15, lq = lane >> 4;

  f32x4 acc[4][4];
#pragma unroll
  for (int mi = 0; mi < 4; ++mi)
#pragma unroll
    for (int ni = 0; ni < 4; ++ni) acc[mi][ni] = f32x4{0.f, 0.f, 0.f, 0.f};

  const unsigned short* Bsrc = w2t + (size_t)e * OO * HH + (size_t)n0 * HH;

  for (int k0 = 0; k0 < HH; k0 += 64) {
#pragma unroll
    for (int p = 0; p < 4; ++p) {
      int c = p * 256 + t;
      int row = c >> 3, kc = (c & 7) * 8;
      int slot = slotbuf[row];
      uint4 v = *(const uint4*)&h[(size_t)slot * HH + k0 + kc];
      *(uint4*)&Abuf[row * 72 + kc] = v;
    }
#pragma unroll
    for (int p = 0; p < 4; ++p) {
      int c = p * 256 + t;
      int row = c >> 3, kc = (c & 7) * 8;
      uint4 v = *(const uint4*)&Bsrc[(size_t)row * HH + k0 + kc];
      *(uint4*)&Bbuf[row * 72 + kc] = v;
    }
    __syncthreads();
#pragma unroll
    for (int ks = 0; ks < 64; ks += 32) {
      bf16x8 af[4], bf[4];
#pragma unroll
      for (int mi = 0; mi < 4; ++mi)
        af[mi] = *(const bf16x8*)&Abuf[(wm + mi * 16 + lm) * 72 + ks + lq * 8];
#pragma unroll
      for (int ni = 0; ni < 4; ++ni)
        bf[ni] = *(const bf16x8*)&Bbuf[(wn + ni * 16 + lm) * 72 + ks + lq * 8];
#pragma unroll
      for (int mi = 0; mi < 4; ++mi)
#pragma unroll
        for (int ni = 0; ni < 4; ++ni)
          acc[mi][ni] = __builtin_amdgcn_mfma_f32_16x16x32_bf16(af[mi], bf[ni], acc[mi][ni], 0, 0, 0);
    }
    __syncthreads();
  }

#pragma unroll
  for (int ni = 0; ni < 4; ++ni) {
    int ncol = n0 + wn + ni * 16 + lm;
    float bias = b2[e * OO + ncol];
#pragma unroll
    for (int mi = 0; mi < 4; ++mi) {
      int mbase = wm + mi * 16 + lq * 4;
#pragma unroll
      for (int r = 0; r < 4; ++r) {
        int mrow = mbase + r;
        if (m0 + mrow < cnt_e) {
          float v = (acc[mi][ni][r] + bias) * rwbuf[mrow];
          int slot = slotbuf[mrow];
          atomicAdd(&out[(size_t)(slot >> 1) * OO + ncol], v);
        }
      }
    }
  }
}

extern "C" void kernel_launch(void* const* d_in, const int* in_sizes, int n_in,
                              void* d_out, int out_size, void* d_ws, size_t ws_size,
                              hipStream_t stream) {
  const float* x  = (const float*)d_in[0];
  const float* gw = (const float*)d_in[1];
  const float* gb = (const float*)d_in[2];
  const float* w1 = (const float*)d_in[3];
  const float* b1 = (const float*)d_in[4];
  const float* w2 = (const float*)d_in[5];
  const float* b2 = (const float*)d_in[6];
  float* out = (float*)d_out;
  char* ws = (char*)d_ws;

  // ws layout
  int*            cnt  = (int*)(ws);                      // 32 B
  int*            list = (int*)(ws + 1024);               // 8*4096*4 = 128 KB
  float*          rw   = (float*)(ws + (256u << 10));     // 32 KB
  unsigned short* xb   = (unsigned short*)(ws + (1u  << 20));  // 8 MB
  unsigned short* wt   = (unsigned short*)(ws + (16u << 20));  // 64 MB (w1t then w2t)
  unsigned short* h    = (unsigned short*)(ws + (88u << 20));  // 64 MB
  size_t need = (88u << 20) + (size_t)2 * BT * HH * 2;
  if (ws_size < need) return;  // workspace too small -> visible failure

  hipMemsetAsync(cnt, 0, 1024, stream);
  hipMemsetAsync(out, 0, (size_t)BT * OO * sizeof(float), stream);

  cvt_x_k<<<BT * DD / 1024, 256, 0, stream>>>(x, xb);
  router_k<<<BT / 4, 256, 0, stream>>>(x, gw, gb, cnt, list, rw);
  cvt_t_k<<<dim3(DD / 64, HH / 64, EE), 256, 0, stream>>>(w1, wt, DD, HH);
  gemm1_k<<<dim3(32, HH / 128, EE), 256, 0, stream>>>(xb, wt, b1, cnt, list, h);
  cvt_t_k<<<dim3(HH / 64, OO / 64, EE), 256, 0, stream>>>(w2, wt, HH, OO);
  gemm2_k<<<dim3(32, OO / 128, EE), 256, 0, stream>>>(h, wt, b2, cnt, list, rw, out);
}

// Round 2
// 752.725 us; speedup vs baseline: 1.8534x; 1.8534x over previous
//
#include <hip/hip_runtime.h>
#include <stdint.h>

typedef short bf16x8 __attribute__((ext_vector_type(8)));
typedef float f32x4  __attribute__((ext_vector_type(4)));

constexpr int BT = 4096;   // tokens
constexpr int DD = 1024;   // model dim
constexpr int OO = 1024;   // output dim
constexpr int EE = 8;      // experts
constexpr int HH = 4096;   // hidden dim

__device__ __forceinline__ unsigned short f2bf(float f) {
  unsigned u = __float_as_uint(f);
  u += 0x7fffu + ((u >> 16) & 1u);   // round-to-nearest-even
  return (unsigned short)(u >> 16);
}

// async 16B global->LDS. LDS dest must be wave-uniform base; HW adds lane*16.
__device__ __forceinline__ void glds16(const unsigned short* g, unsigned short* l) {
  __builtin_amdgcn_global_load_lds(
      (const __attribute__((address_space(1))) void*)g,
      (__attribute__((address_space(3))) void*)l, 16, 0, 0);
}

// ---------- router: logits, top-2 softmax, expert lists; also x -> bf16 ----------
__global__ __launch_bounds__(256) void router_k(const float* __restrict__ x,
                                                const float* __restrict__ gw,
                                                const float* __restrict__ gb,
                                                unsigned short* __restrict__ xb,
                                                int* __restrict__ cnt,
                                                int* __restrict__ list,
                                                float* __restrict__ rw) {
  int wave = threadIdx.x >> 6, lane = threadIdx.x & 63;
  int b = blockIdx.x * 4 + wave;
  const float* xrow = x + (size_t)b * DD;
  float acc[8];
#pragma unroll
  for (int e = 0; e < 8; ++e) acc[e] = 0.f;
#pragma unroll
  for (int i = 0; i < 4; ++i) {
    int d0 = i * 256 + lane * 4;
    float4 v = *(const float4*)&xrow[d0];
    unsigned lo = (unsigned)f2bf(v.x) | ((unsigned)f2bf(v.y) << 16);
    unsigned hi = (unsigned)f2bf(v.z) | ((unsigned)f2bf(v.w) << 16);
    *(uint2*)&xb[(size_t)b * DD + d0] = make_uint2(lo, hi);
    const float* g0 = &gw[(size_t)d0 * 8];
    float fv[4] = {v.x, v.y, v.z, v.w};
#pragma unroll
    for (int q = 0; q < 4; ++q) {
      float4 ga = *(const float4*)&g0[q * 8];
      float4 gc = *(const float4*)&g0[q * 8 + 4];
      acc[0] += fv[q] * ga.x; acc[1] += fv[q] * ga.y;
      acc[2] += fv[q] * ga.z; acc[3] += fv[q] * ga.w;
      acc[4] += fv[q] * gc.x; acc[5] += fv[q] * gc.y;
      acc[6] += fv[q] * gc.z; acc[7] += fv[q] * gc.w;
    }
  }
#pragma unroll
  for (int off = 32; off > 0; off >>= 1) {
#pragma unroll
    for (int e = 0; e < 8; ++e) acc[e] += __shfl_down(acc[e], off);
  }
  if (lane == 0) {
    float v[8];
#pragma unroll
    for (int e = 0; e < 8; ++e) v[e] = acc[e] + gb[e];
    int i0 = 0;
#pragma unroll
    for (int e = 1; e < 8; ++e) if (v[e] > v[i0]) i0 = e;
    int i1 = (i0 == 0) ? 1 : 0;
#pragma unroll
    for (int e = 0; e < 8; ++e) if (e != i0 && v[e] > v[i1]) i1 = e;
    float e1 = __expf(v[i1] - v[i0]);
    float inv = 1.0f / (1.0f + e1);
    int p0 = atomicAdd(&cnt[i0], 1);
    list[i0 * BT + p0] = 2 * b;     rw[2 * b]     = inv;
    int p1 = atomicAdd(&cnt[i1], 1);
    list[i1 * BT + p1] = 2 * b + 1; rw[2 * b + 1] = e1 * inv;
  }
}

// ---------- tile map: flat list of (expert, m0) tiles; ntiles in [64,71] ----------
__global__ void tilemap_k(const int* __restrict__ cnt, int* __restrict__ tmap,
                          int* __restrict__ ntiles) {
  if (threadIdx.x == 0 && blockIdx.x == 0) {
    int t = 0;
    for (int e = 0; e < EE; ++e) {
      int c = cnt[e];
      for (int m0 = 0; m0 < c; m0 += 128) { tmap[2 * t] = e; tmap[2 * t + 1] = m0; ++t; }
    }
    *ntiles = t;
  }
}

// ------- transpose+convert: src fp32 [E][R][C] -> dst bf16 [E][C][R] -------
__global__ __launch_bounds__(256) void cvt_t_k(const float* __restrict__ src,
                                               unsigned short* __restrict__ dst,
                                               int R, int C) {
  __shared__ unsigned short tile[64][68];
  int e = blockIdx.z;
  const float* s = src + (size_t)e * R * C;
  unsigned short* d = dst + (size_t)e * R * C;
  int r0 = blockIdx.x << 6, c0 = blockIdx.y << 6;
  int t = threadIdx.x;
#pragma unroll
  for (int p = 0; p < 4; ++p) {
    int ch = p * 256 + t;
    int rr = ch >> 4, cc = (ch & 15) << 2;
    float4 v = *(const float4*)&s[(size_t)(r0 + rr) * C + c0 + cc];
    unsigned lo = (unsigned)f2bf(v.x) | ((unsigned)f2bf(v.y) << 16);
    unsigned hi = (unsigned)f2bf(v.z) | ((unsigned)f2bf(v.w) << 16);
    *(uint2*)&tile[rr][cc] = make_uint2(lo, hi);
  }
  __syncthreads();
#pragma unroll
  for (int p = 0; p < 4; ++p) {
    int ch = p * 256 + t;
    int cc = ch >> 4, rr = (ch & 15) << 2;
    unsigned short v0 = tile[rr + 0][cc];
    unsigned short v1 = tile[rr + 1][cc];
    unsigned short v2 = tile[rr + 2][cc];
    unsigned short v3 = tile[rr + 3][cc];
    unsigned lo = (unsigned)v0 | ((unsigned)v1 << 16);
    unsigned hi = (unsigned)v2 | ((unsigned)v3 << 16);
    *(uint2*)&d[(size_t)(c0 + cc) * R + r0 + rr] = make_uint2(lo, hi);
  }
}

// ---------------- GEMM1: h[slot] = relu(x[tok] @ w1[e] + b1[e]) ----------------
__global__ __launch_bounds__(256, 3) void gemm1_k(const unsigned short* __restrict__ xb,
                                                  const unsigned short* __restrict__ w1t,
                                                  const float* __restrict__ b1,
                                                  const int* __restrict__ cnt,
                                                  const int* __restrict__ list,
                                                  const int* __restrict__ tmap,
                                                  const int* __restrict__ ntiles,
                                                  unsigned short* __restrict__ h) {
  int ti = blockIdx.x;
  if (ti >= *ntiles) return;
  int e = tmap[2 * ti], m0 = tmap[2 * ti + 1];
  int cnt_e = cnt[e];
  int n0 = blockIdx.y * 128;

  __shared__ int slotbuf[128];
  __shared__ __align__(16) unsigned short Ash[128 * 64];  // [row][64], unpadded for glds
  __shared__ __align__(16) unsigned short Bsh[128 * 64];

  int t = threadIdx.x;
  if (t < 128) {
    int r = m0 + t;
    slotbuf[t] = list[e * BT + (r < cnt_e ? r : 0)];
  }
  __syncthreads();

  int w = t >> 6, l = t & 63;
  int lm = l & 15, lq = l >> 4;
  int wm = (w & 1) * 64, wn = (w >> 1) * 64;

  const unsigned short* Bsrc = w1t + (size_t)e * HH * DD + (size_t)n0 * DD;

  // per-wave staging: instr idx=4w+j covers rows [idx*8, idx*8+8), lane l -> row idx*8+(l>>3), k-off (l&7)*8
  const unsigned short* aS[4];
  const unsigned short* bS[4];
  unsigned short* aL[4];
  unsigned short* bL[4];
#pragma unroll
  for (int j = 0; j < 4; ++j) {
    int idx = 4 * w + j;
    int row = idx * 8 + (l >> 3);
    int koff = (l & 7) * 8;
    int tok = slotbuf[row] >> 1;
    aS[j] = xb + (size_t)tok * DD + koff;
    bS[j] = Bsrc + (size_t)row * DD + koff;
    aL[j] = &Ash[idx * 512];
    bL[j] = &Bsh[idx * 512];
  }

  f32x4 acc[4][4];
#pragma unroll
  for (int mi = 0; mi < 4; ++mi)
#pragma unroll
    for (int ni = 0; ni < 4; ++ni) acc[mi][ni] = f32x4{0.f, 0.f, 0.f, 0.f};

  for (int k0 = 0; k0 < DD; k0 += 64) {
#pragma unroll
    for (int j = 0; j < 4; ++j) glds16(aS[j] + k0, aL[j]);
#pragma unroll
    for (int j = 0; j < 4; ++j) glds16(bS[j] + k0, bL[j]);
    __syncthreads();
#pragma unroll
    for (int ks = 0; ks < 2; ++ks) {
      bf16x8 af[4], bfr[4];
      int kb = ks * 32 + lq * 8;
#pragma unroll
      for (int mi = 0; mi < 4; ++mi)
        af[mi] = *(const bf16x8*)&Ash[(wm + mi * 16 + lm) * 64 + kb];
#pragma unroll
      for (int ni = 0; ni < 4; ++ni)
        bfr[ni] = *(const bf16x8*)&Bsh[(wn + ni * 16 + lm) * 64 + kb];
#pragma unroll
      for (int mi = 0; mi < 4; ++mi)
#pragma unroll
        for (int ni = 0; ni < 4; ++ni)
          acc[mi][ni] = __builtin_amdgcn_mfma_f32_16x16x32_bf16(af[mi], bfr[ni], acc[mi][ni], 0, 0, 0);
    }
    __syncthreads();
  }

#pragma unroll
  for (int ni = 0; ni < 4; ++ni) {
    int ncol = n0 + wn + ni * 16 + lm;
    float bias = b1[e * HH + ncol];
#pragma unroll
    for (int mi = 0; mi < 4; ++mi) {
      int mbase = wm + mi * 16 + lq * 4;
#pragma unroll
      for (int r = 0; r < 4; ++r) {
        int mrow = mbase + r;
        if (m0 + mrow < cnt_e) {
          float v = fmaxf(acc[mi][ni][r] + bias, 0.0f);
          h[(size_t)slotbuf[mrow] * HH + ncol] = f2bf(v);
        }
      }
    }
  }
}

// -------- GEMM2 (split-K): out[tok] += rw[slot] * (h[slot] @ w2[e] + b2[e]) --------
__global__ __launch_bounds__(256, 3) void gemm2_k(const unsigned short* __restrict__ h,
                                                  const unsigned short* __restrict__ w2t,
                                                  const float* __restrict__ b2,
                                                  const int* __restrict__ cnt,
                                                  const int* __restrict__ list,
                                                  const int* __restrict__ tmap,
                                                  const int* __restrict__ ntiles,
                                                  const float* __restrict__ rw,
                                                  float* __restrict__ out) {
  int ti = blockIdx.x;
  if (ti >= *ntiles) return;
  int e = tmap[2 * ti], m0 = tmap[2 * ti + 1];
  int cnt_e = cnt[e];
  int n0 = blockIdx.y * 128;
  int kb0 = blockIdx.z * (HH / 4);

  __shared__ int slotbuf[128];
  __shared__ float rwbuf[128];
  __shared__ __align__(16) unsigned short Ash[128 * 64];
  __shared__ __align__(16) unsigned short Bsh[128 * 64];

  int t = threadIdx.x;
  if (t < 128) {
    int r = m0 + t;
    int s_ = list[e * BT + (r < cnt_e ? r : 0)];
    slotbuf[t] = s_;
    rwbuf[t] = rw[s_];
  }
  __syncthreads();

  int w = t >> 6, l = t & 63;
  int lm = l & 15, lq = l >> 4;
  int wm = (w & 1) * 64, wn = (w >> 1) * 64;

  const unsigned short* Bsrc = w2t + (size_t)e * OO * HH + (size_t)n0 * HH;

  const unsigned short* aS[4];
  const unsigned short* bS[4];
  unsigned short* aL[4];
  unsigned short* bL[4];
#pragma unroll
  for (int j = 0; j < 4; ++j) {
    int idx = 4 * w + j;
    int row = idx * 8 + (l >> 3);
    int koff = (l & 7) * 8;
    int slot = slotbuf[row];
    aS[j] = h + (size_t)slot * HH + kb0 + koff;
    bS[j] = Bsrc + (size_t)row * HH + kb0 + koff;
    aL[j] = &Ash[idx * 512];
    bL[j] = &Bsh[idx * 512];
  }

  f32x4 acc[4][4];
#pragma unroll
  for (int mi = 0; mi < 4; ++mi)
#pragma unroll
    for (int ni = 0; ni < 4; ++ni) acc[mi][ni] = f32x4{0.f, 0.f, 0.f, 0.f};

  for (int k0 = 0; k0 < HH / 4; k0 += 64) {
#pragma unroll
    for (int j = 0; j < 4; ++j) glds16(aS[j] + k0, aL[j]);
#pragma unroll
    for (int j = 0; j < 4; ++j) glds16(bS[j] + k0, bL[j]);
    __syncthreads();
#pragma unroll
    for (int ks = 0; ks < 2; ++ks) {
      bf16x8 af[4], bfr[4];
      int kb = ks * 32 + lq * 8;
#pragma unroll
      for (int mi = 0; mi < 4; ++mi)
        af[mi] = *(const bf16x8*)&Ash[(wm + mi * 16 + lm) * 64 + kb];
#pragma unroll
      for (int ni = 0; ni < 4; ++ni)
        bfr[ni] = *(const bf16x8*)&Bsh[(wn + ni * 16 + lm) * 64 + kb];
#pragma unroll
      for (int mi = 0; mi < 4; ++mi)
#pragma unroll
        for (int ni = 0; ni < 4; ++ni)
          acc[mi][ni] = __builtin_amdgcn_mfma_f32_16x16x32_bf16(af[mi], bfr[ni], acc[mi][ni], 0, 0, 0);
    }
    __syncthreads();
  }

  bool addbias = (blockIdx.z == 0);
#pragma unroll
  for (int ni = 0; ni < 4; ++ni) {
    int ncol = n0 + wn + ni * 16 + lm;
    float bias = addbias ? b2[e * OO + ncol] : 0.0f;
#pragma unroll
    for (int mi = 0; mi < 4; ++mi) {
      int mbase = wm + mi * 16 + lq * 4;
#pragma unroll
      for (int r = 0; r < 4; ++r) {
        int mrow = mbase + r;
        if (m0 + mrow < cnt_e) {
          float v = (acc[mi][ni][r] + bias) * rwbuf[mrow];
          int slot = slotbuf[mrow];
          atomicAdd(&out[(size_t)(slot >> 1) * OO + ncol], v);
        }
      }
    }
  }
}

extern "C" void kernel_launch(void* const* d_in, const int* in_sizes, int n_in,
                              void* d_out, int out_size, void* d_ws, size_t ws_size,
                              hipStream_t stream) {
  const float* x  = (const float*)d_in[0];
  const float* gw = (const float*)d_in[1];
  const float* gb = (const float*)d_in[2];
  const float* w1 = (const float*)d_in[3];
  const float* b1 = (const float*)d_in[4];
  const float* w2 = (const float*)d_in[5];
  const float* b2 = (const float*)d_in[6];
  float* out = (float*)d_out;
  char* ws = (char*)d_ws;

  // ws layout
  int*            cnt    = (int*)(ws);                         // 32 B
  int*            list   = (int*)(ws + 1024);                  // 128 KB
  float*          rw     = (float*)(ws + (256u << 10));        // 32 KB
  int*            tmap   = (int*)(ws + (512u << 10));          // 576 B
  int*            ntiles = (int*)(ws + (520u << 10));          // 4 B
  unsigned short* xb     = (unsigned short*)(ws + (1u  << 20)); // 8 MB
  unsigned short* wt     = (unsigned short*)(ws + (16u << 20)); // 64 MB (w1t, then w2t)
  unsigned short* h      = (unsigned short*)(ws + (88u << 20)); // 64 MB
  size_t need = (88u << 20) + (size_t)2 * BT * HH * 2;
  if (ws_size < need) return;

  hipMemsetAsync(cnt, 0, 1024, stream);
  hipMemsetAsync(out, 0, (size_t)BT * OO * sizeof(float), stream);

  router_k<<<BT / 4, 256, 0, stream>>>(x, gw, gb, xb, cnt, list, rw);
  tilemap_k<<<1, 64, 0, stream>>>(cnt, tmap, ntiles);
  cvt_t_k<<<dim3(DD / 64, HH / 64, EE), 256, 0, stream>>>(w1, wt, DD, HH);
  gemm1_k<<<dim3(72, HH / 128), 256, 0, stream>>>(xb, wt, b1, cnt, list, tmap, ntiles, h);
  cvt_t_k<<<dim3(HH / 64, OO / 64, EE), 256, 0, stream>>>(w2, wt, HH, OO);
  gemm2_k<<<dim3(72, OO / 128, 4), 256, 0, stream>>>(h, wt, b2, cnt, list, tmap, ntiles, rw, out);
}

// Round 3
// 718.897 us; speedup vs baseline: 1.9406x; 1.0471x over previous
//
#include <hip/hip_runtime.h>
#include <stdint.h>

typedef short bf16x8 __attribute__((ext_vector_type(8)));
typedef float f32x4  __attribute__((ext_vector_type(4)));

constexpr int BT = 4096;   // tokens
constexpr int DD = 1024;   // model dim
constexpr int OO = 1024;   // output dim
constexpr int EE = 8;      // experts
constexpr int HH = 4096;   // hidden dim
constexpr int SLOTS = 2 * BT;  // 8192

__device__ __forceinline__ unsigned short f2bf(float f) {
  unsigned u = __float_as_uint(f);
  u += 0x7fffu + ((u >> 16) & 1u);   // round-to-nearest-even
  return (unsigned short)(u >> 16);
}

// async 16B global->LDS. LDS dest is wave-uniform base; HW adds lane*16.
__device__ __forceinline__ void glds16(const unsigned short* g, unsigned short* l) {
  __builtin_amdgcn_global_load_lds(
      (const __attribute__((address_space(1))) void*)g,
      (__attribute__((address_space(3))) void*)l, 16, 0, 0);
}

// ---------- router: logits, top-2 softmax, expert lists; also x -> bf16 ----------
__global__ __launch_bounds__(256) void router_k(const float* __restrict__ x,
                                                const float* __restrict__ gw,
                                                const float* __restrict__ gb,
                                                unsigned short* __restrict__ xb,
                                                int* __restrict__ cnt,
                                                int* __restrict__ list,
                                                float* __restrict__ rw) {
  int wave = threadIdx.x >> 6, lane = threadIdx.x & 63;
  int b = blockIdx.x * 4 + wave;
  const float* xrow = x + (size_t)b * DD;
  float acc[8];
#pragma unroll
  for (int e = 0; e < 8; ++e) acc[e] = 0.f;
#pragma unroll
  for (int i = 0; i < 4; ++i) {
    int d0 = i * 256 + lane * 4;
    float4 v = *(const float4*)&xrow[d0];
    unsigned lo = (unsigned)f2bf(v.x) | ((unsigned)f2bf(v.y) << 16);
    unsigned hi = (unsigned)f2bf(v.z) | ((unsigned)f2bf(v.w) << 16);
    *(uint2*)&xb[(size_t)b * DD + d0] = make_uint2(lo, hi);
    const float* g0 = &gw[(size_t)d0 * 8];
    float fv[4] = {v.x, v.y, v.z, v.w};
#pragma unroll
    for (int q = 0; q < 4; ++q) {
      float4 ga = *(const float4*)&g0[q * 8];
      float4 gc = *(const float4*)&g0[q * 8 + 4];
      acc[0] += fv[q] * ga.x; acc[1] += fv[q] * ga.y;
      acc[2] += fv[q] * ga.z; acc[3] += fv[q] * ga.w;
      acc[4] += fv[q] * gc.x; acc[5] += fv[q] * gc.y;
      acc[6] += fv[q] * gc.z; acc[7] += fv[q] * gc.w;
    }
  }
#pragma unroll
  for (int off = 32; off > 0; off >>= 1) {
#pragma unroll
    for (int e = 0; e < 8; ++e) acc[e] += __shfl_down(acc[e], off);
  }
  if (lane == 0) {
    float v[8];
#pragma unroll
    for (int e = 0; e < 8; ++e) v[e] = acc[e] + gb[e];
    int i0 = 0;
#pragma unroll
    for (int e = 1; e < 8; ++e) if (v[e] > v[i0]) i0 = e;
    int i1 = (i0 == 0) ? 1 : 0;
#pragma unroll
    for (int e = 0; e < 8; ++e) if (e != i0 && v[e] > v[i1]) i1 = e;
    float e1 = __expf(v[i1] - v[i0]);
    float inv = 1.0f / (1.0f + e1);
    int p0 = atomicAdd(&cnt[i0], 1);
    list[i0 * BT + p0] = 2 * b;     rw[2 * b]     = inv;
    int p1 = atomicAdd(&cnt[i1], 1);
    list[i1 * BT + p1] = 2 * b + 1; rw[2 * b + 1] = e1 * inv;
  }
}

// ---- tile map: (expert, m0, compacted_base) per 128-row tile; ntiles in [64,71] ----
__global__ void tilemap_k(const int* __restrict__ cnt, int* __restrict__ tmap,
                          int* __restrict__ ntiles) {
  if (threadIdx.x == 0 && blockIdx.x == 0) {
    int t = 0, basewalk = 0;
    for (int e = 0; e < EE; ++e) {
      int c = cnt[e];
      for (int m0 = 0; m0 < c; m0 += 128) {
        tmap[4 * t] = e; tmap[4 * t + 1] = m0; tmap[4 * t + 2] = basewalk + m0; ++t;
      }
      basewalk += c;
    }
    *ntiles = t;
  }
}

// ------- transpose+convert: src fp32 [E][R][C] -> dst bf16 [E][C][R] -------
__global__ __launch_bounds__(256) void cvt_t_k(const float* __restrict__ src,
                                               unsigned short* __restrict__ dst,
                                               int R, int C) {
  __shared__ unsigned short tile[64][66];
  int e = blockIdx.z;
  const float* s = src + (size_t)e * R * C;
  unsigned short* d = dst + (size_t)e * R * C;
  int r0 = blockIdx.x << 6, c0 = blockIdx.y << 6;
  int t = threadIdx.x;
#pragma unroll
  for (int p = 0; p < 4; ++p) {
    int ch = p * 256 + t;
    int rr = ch >> 4, cc = (ch & 15) << 2;
    float4 v = *(const float4*)&s[(size_t)(r0 + rr) * C + c0 + cc];
    unsigned lo = (unsigned)f2bf(v.x) | ((unsigned)f2bf(v.y) << 16);
    unsigned hi = (unsigned)f2bf(v.z) | ((unsigned)f2bf(v.w) << 16);
    *(uint2*)&tile[rr][cc] = make_uint2(lo, hi);
  }
  __syncthreads();
#pragma unroll
  for (int p = 0; p < 4; ++p) {
    int ch = p * 256 + t;
    int cc = ch >> 4, rr = (ch & 15) << 2;
    unsigned short v0 = tile[rr + 0][cc];
    unsigned short v1 = tile[rr + 1][cc];
    unsigned short v2 = tile[rr + 2][cc];
    unsigned short v3 = tile[rr + 3][cc];
    unsigned lo = (unsigned)v0 | ((unsigned)v1 << 16);
    unsigned hi = (unsigned)v2 | ((unsigned)v3 << 16);
    *(uint2*)&d[(size_t)(c0 + cc) * R + r0 + rr] = make_uint2(lo, hi);
  }
}

// ----- GEMM1: hc[base+row] = relu(x[tok] @ w1[e] + b1[e]), compacted layout -----
// grid: (HH/128, 72); x = n-tile (fast -> XCD spread), y = expert m-tile
__global__ __launch_bounds__(256, 4) void gemm1_k(const unsigned short* __restrict__ xb,
                                                  const unsigned short* __restrict__ w1t,
                                                  const float* __restrict__ b1,
                                                  const int* __restrict__ cnt,
                                                  const int* __restrict__ list,
                                                  const int* __restrict__ tmap,
                                                  const int* __restrict__ ntiles,
                                                  unsigned short* __restrict__ hc) {
  int ti = blockIdx.y;
  if (ti >= *ntiles) return;
  int e = tmap[4 * ti], m0 = tmap[4 * ti + 1], base = tmap[4 * ti + 2];
  int cnt_e = cnt[e];
  int n0 = blockIdx.x * 128;

  __shared__ int slotbuf[128];
  __shared__ __align__(16) unsigned short Ash[128 * 64];
  __shared__ __align__(16) unsigned short Bsh[128 * 64];

  int t = threadIdx.x;
  if (t < 128) {
    int r = m0 + t;
    slotbuf[t] = list[e * BT + (r < cnt_e ? r : 0)];
  }
  __syncthreads();

  int w = t >> 6, l = t & 63;
  int lm = l & 15, lq = l >> 4;
  int wm = (w & 1) * 64, wn = (w >> 1) * 64;

  const unsigned short* Bsrc = w1t + (size_t)e * HH * DD + (size_t)n0 * DD;

  const unsigned short* aS[4];
  const unsigned short* bS[4];
  unsigned short* aL[4];
  unsigned short* bL[4];
#pragma unroll
  for (int j = 0; j < 4; ++j) {
    int idx = 4 * w + j;
    int row = idx * 8 + (l >> 3);
    int koff = (l & 7) * 8;
    int tok = slotbuf[row] >> 1;
    aS[j] = xb + (size_t)tok * DD + koff;
    bS[j] = Bsrc + (size_t)row * DD + koff;
    aL[j] = &Ash[idx * 512];
    bL[j] = &Bsh[idx * 512];
  }

  f32x4 acc[4][4];
#pragma unroll
  for (int mi = 0; mi < 4; ++mi)
#pragma unroll
    for (int ni = 0; ni < 4; ++ni) acc[mi][ni] = f32x4{0.f, 0.f, 0.f, 0.f};

  for (int k0 = 0; k0 < DD; k0 += 64) {
#pragma unroll
    for (int j = 0; j < 4; ++j) glds16(aS[j] + k0, aL[j]);
#pragma unroll
    for (int j = 0; j < 4; ++j) glds16(bS[j] + k0, bL[j]);
    __syncthreads();
#pragma unroll
    for (int ks = 0; ks < 2; ++ks) {
      bf16x8 af[4], bfr[4];
      int kb = ks * 32 + lq * 8;
#pragma unroll
      for (int mi = 0; mi < 4; ++mi)
        af[mi] = *(const bf16x8*)&Ash[(wm + mi * 16 + lm) * 64 + kb];
#pragma unroll
      for (int ni = 0; ni < 4; ++ni)
        bfr[ni] = *(const bf16x8*)&Bsh[(wn + ni * 16 + lm) * 64 + kb];
#pragma unroll
      for (int mi = 0; mi < 4; ++mi)
#pragma unroll
        for (int ni = 0; ni < 4; ++ni)
          acc[mi][ni] = __builtin_amdgcn_mfma_f32_16x16x32_bf16(af[mi], bfr[ni], acc[mi][ni], 0, 0, 0);
    }
    __syncthreads();
  }

#pragma unroll
  for (int ni = 0; ni < 4; ++ni) {
    int ncol = n0 + wn + ni * 16 + lm;
    float bias = b1[e * HH + ncol];
#pragma unroll
    for (int mi = 0; mi < 4; ++mi) {
      int mbase = wm + mi * 16 + lq * 4;
#pragma unroll
      for (int r = 0; r < 4; ++r) {
        int mrow = mbase + r;
        if (m0 + mrow < cnt_e) {
          float v = fmaxf(acc[mi][ni][r] + bias, 0.0f);
          hc[(size_t)(base + mrow) * HH + ncol] = f2bf(v);
        }
      }
    }
  }
}

// -- GEMM2: y[z][slot] = rw*(hc_rows @ w2[e] + b2[e] [z==0]) ; or atomic into out --
// grid: (OO/128, 72, zsplit)
__global__ __launch_bounds__(256, 4) void gemm2_k(const unsigned short* __restrict__ hc,
                                                  const unsigned short* __restrict__ w2t,
                                                  const float* __restrict__ b2,
                                                  const int* __restrict__ cnt,
                                                  const int* __restrict__ list,
                                                  const int* __restrict__ tmap,
                                                  const int* __restrict__ ntiles,
                                                  const float* __restrict__ rw,
                                                  float* __restrict__ ybuf,
                                                  float* __restrict__ out) {
  int ti = blockIdx.y;
  if (ti >= *ntiles) return;
  int e = tmap[4 * ti], m0 = tmap[4 * ti + 1], base = tmap[4 * ti + 2];
  int cnt_e = cnt[e];
  int n0 = blockIdx.x * 128;
  int ksl = HH / gridDim.z;
  int kb0 = blockIdx.z * ksl;

  __shared__ int slotbuf[128];
  __shared__ float rwbuf[128];
  __shared__ __align__(16) unsigned short Ash[128 * 64];
  __shared__ __align__(16) unsigned short Bsh[128 * 64];

  int t = threadIdx.x;
  if (t < 128) {
    int r = m0 + t;
    int s_ = list[e * BT + (r < cnt_e ? r : 0)];
    slotbuf[t] = s_;
    rwbuf[t] = rw[s_];
  }
  __syncthreads();

  int w = t >> 6, l = t & 63;
  int lm = l & 15, lq = l >> 4;
  int wm = (w & 1) * 64, wn = (w >> 1) * 64;

  const unsigned short* Bsrc = w2t + (size_t)e * OO * HH + (size_t)n0 * HH;

  const unsigned short* aS[4];
  const unsigned short* bS[4];
  unsigned short* aL[4];
  unsigned short* bL[4];
#pragma unroll
  for (int j = 0; j < 4; ++j) {
    int idx = 4 * w + j;
    int row = idx * 8 + (l >> 3);
    int koff = (l & 7) * 8;
    aS[j] = hc + (size_t)(base + row) * HH + kb0 + koff;   // contiguous compacted rows
    bS[j] = Bsrc + (size_t)row * HH + kb0 + koff;
    aL[j] = &Ash[idx * 512];
    bL[j] = &Bsh[idx * 512];
  }

  f32x4 acc[4][4];
#pragma unroll
  for (int mi = 0; mi < 4; ++mi)
#pragma unroll
    for (int ni = 0; ni < 4; ++ni) acc[mi][ni] = f32x4{0.f, 0.f, 0.f, 0.f};

  for (int k0 = 0; k0 < ksl; k0 += 64) {
#pragma unroll
    for (int j = 0; j < 4; ++j) glds16(aS[j] + k0, aL[j]);
#pragma unroll
    for (int j = 0; j < 4; ++j) glds16(bS[j] + k0, bL[j]);
    __syncthreads();
#pragma unroll
    for (int ks = 0; ks < 2; ++ks) {
      bf16x8 af[4], bfr[4];
      int kb = ks * 32 + lq * 8;
#pragma unroll
      for (int mi = 0; mi < 4; ++mi)
        af[mi] = *(const bf16x8*)&Ash[(wm + mi * 16 + lm) * 64 + kb];
#pragma unroll
      for (int ni = 0; ni < 4; ++ni)
        bfr[ni] = *(const bf16x8*)&Bsh[(wn + ni * 16 + lm) * 64 + kb];
#pragma unroll
      for (int mi = 0; mi < 4; ++mi)
#pragma unroll
        for (int ni = 0; ni < 4; ++ni)
          acc[mi][ni] = __builtin_amdgcn_mfma_f32_16x16x32_bf16(af[mi], bfr[ni], acc[mi][ni], 0, 0, 0);
    }
    __syncthreads();
  }

  bool addbias = (blockIdx.z == 0);
  size_t ybase = (size_t)blockIdx.z * SLOTS;
#pragma unroll
  for (int ni = 0; ni < 4; ++ni) {
    int ncol = n0 + wn + ni * 16 + lm;
    float bias = addbias ? b2[e * OO + ncol] : 0.0f;
#pragma unroll
    for (int mi = 0; mi < 4; ++mi) {
      int mbase = wm + mi * 16 + lq * 4;
#pragma unroll
      for (int r = 0; r < 4; ++r) {
        int mrow = mbase + r;
        if (m0 + mrow < cnt_e) {
          float v = (acc[mi][ni][r] + bias) * rwbuf[mrow];
          int slot = slotbuf[mrow];
          if (ybuf) ybuf[(ybase + slot) * OO + ncol] = v;
          else      atomicAdd(&out[(size_t)(slot >> 1) * OO + ncol], v);
        }
      }
    }
  }
}

// ---- combine: out[b] = sum_z (y[z][2b] + y[z][2b+1]) ----
__global__ __launch_bounds__(256) void combine_k(const float* __restrict__ y,
                                                 float* __restrict__ out, int nz) {
  int i = blockIdx.x * 256 + threadIdx.x;        // one float4 of out
  int b = i >> 8, c = i & 255;                   // 256 float4 per row
  f32x4 acc = {0.f, 0.f, 0.f, 0.f};
  for (int z = 0; z < nz; ++z) {
#pragma unroll
    for (int k = 0; k < 2; ++k) {
      const float4 v = *(const float4*)&y[((size_t)z * SLOTS + 2 * b + k) * OO + c * 4];
      acc[0] += v.x; acc[1] += v.y; acc[2] += v.z; acc[3] += v.w;
    }
  }
  *(f32x4*)&out[(size_t)b * OO + c * 4] = acc;
}

extern "C" void kernel_launch(void* const* d_in, const int* in_sizes, int n_in,
                              void* d_out, int out_size, void* d_ws, size_t ws_size,
                              hipStream_t stream) {
  const float* x  = (const float*)d_in[0];
  const float* gw = (const float*)d_in[1];
  const float* gb = (const float*)d_in[2];
  const float* w1 = (const float*)d_in[3];
  const float* b1 = (const float*)d_in[4];
  const float* w2 = (const float*)d_in[5];
  const float* b2 = (const float*)d_in[6];
  float* out = (float*)d_out;
  char* ws = (char*)d_ws;

  // ws layout
  int*            cnt    = (int*)(ws);                          // 32 B
  int*            ntiles = (int*)(ws + 64);
  int*            tmap   = (int*)(ws + 128);                    // 72*16 B
  float*          rw     = (float*)(ws + 4096);                 // 32 KB
  int*            list   = (int*)(ws + (64u << 10));            // 128 KB
  unsigned short* xb     = (unsigned short*)(ws + (1u  << 20)); // 8 MB
  unsigned short* wt     = (unsigned short*)(ws + (9u  << 20)); // 64 MB (w1t, then w2t)
  unsigned short* hc     = (unsigned short*)(ws + (73u << 20)); // 64 MB + 1 MB slack
  float*          ybuf   = (float*)(ws + (138u << 20));         // up to 64 MB

  size_t need_min = (138u << 20);
  if (ws_size < need_min) return;
  int zsplit;
  float* ypass;
  if (ws_size >= (138u << 20) + (size_t)2 * SLOTS * OO * 4) { zsplit = 2; ypass = ybuf; }
  else if (ws_size >= (138u << 20) + (size_t)SLOTS * OO * 4) { zsplit = 1; ypass = ybuf; }
  else { zsplit = 2; ypass = nullptr; }

  hipMemsetAsync(cnt, 0, 64, stream);
  if (!ypass) hipMemsetAsync(out, 0, (size_t)BT * OO * sizeof(float), stream);

  router_k<<<BT / 4, 256, 0, stream>>>(x, gw, gb, xb, cnt, list, rw);
  tilemap_k<<<1, 64, 0, stream>>>(cnt, tmap, ntiles);
  cvt_t_k<<<dim3(DD / 64, HH / 64, EE), 256, 0, stream>>>(w1, wt, DD, HH);
  gemm1_k<<<dim3(HH / 128, 72), 256, 0, stream>>>(xb, wt, b1, cnt, list, tmap, ntiles, hc);
  cvt_t_k<<<dim3(HH / 64, OO / 64, EE), 256, 0, stream>>>(w2, wt, HH, OO);
  gemm2_k<<<dim3(OO / 128, 72, zsplit), 256, 0, stream>>>(hc, wt, b2, cnt, list, tmap, ntiles, rw, ypass, out);
  if (ypass)
    combine_k<<<BT * OO / 1024, 256, 0, stream>>>(ybuf, out, zsplit);
}